// Round 13
// baseline (251.093 us; speedup 1.0000x reference)
//
#include <hip/hip_runtime.h>

#define M_DIM 16384
#define N_DIM 1024
#define K_DIM 4096

#define BM 256
#define BN 256
#define BK 64
#define NT (K_DIM / BK)

typedef __attribute__((ext_vector_type(4))) float f32x4;
typedef __attribute__((ext_vector_type(8))) short bf16x8;
typedef __attribute__((ext_vector_type(8))) unsigned short u16x8;

static __device__ __forceinline__ short f2bf(float f) {
  union { __bf16 h; short s; } u;
  u.h = (__bf16)f;
  return u.s;
}

static __device__ __forceinline__ void load_lds16(const void* g, void* l) {
  __builtin_amdgcn_global_load_lds(
      (const __attribute__((address_space(1))) void*)g,
      (__attribute__((address_space(3))) void*)l, 16, 0, 0);
}

// ---------- prepass 1: Xb = bf16(X), streaming (proven R5, ~62us) ----------
__global__ __launch_bounds__(256) void xcvt(
    const float* __restrict__ X, unsigned short* __restrict__ Xb) {
  const size_t n8 = (size_t)M_DIM * K_DIM / 8;
  const size_t stride = (size_t)gridDim.x * 256;
  for (size_t i = (size_t)blockIdx.x * 256 + threadIdx.x; i < n8; i += stride) {
    const f32x4 v0 = *(const f32x4*)(X + i * 8);
    const f32x4 v1 = *(const f32x4*)(X + i * 8 + 4);
    u16x8 o;
#pragma unroll
    for (int j = 0; j < 4; ++j) {
      o[j]     = (unsigned short)f2bf(v0[j]);
      o[4 + j] = (unsigned short)f2bf(v1[j]);
    }
    *(u16x8*)(Xb + i * 8) = o;
  }
}

// ---------- prepass 2: WbT[n][k] = bf16(sign(W[k][n])) ----------
__global__ __launch_bounds__(256) void wsign_transpose(
    const float* __restrict__ W, unsigned short* __restrict__ WbT) {
  __shared__ unsigned short tile[64][72];
  const int t  = (int)threadIdx.x;
  const int k0 = (int)(blockIdx.x >> 4) * 64;
  const int n0 = (int)(blockIdx.x & 15) * 64;
#pragma unroll
  for (int p = 0; p < 4; ++p) {
    const int r = p * 16 + (t >> 4);
    const int c = (t & 15) * 4;
    const float* src = W + (size_t)(k0 + r) * N_DIM + n0 + c;
#pragma unroll
    for (int j = 0; j < 4; ++j) {
      const float w = src[j];
      tile[r][c + j] = (w > 0.f) ? (unsigned short)0x3F80u
                                 : ((w < 0.f) ? (unsigned short)0xBF80u
                                              : (unsigned short)0u);
    }
  }
  __syncthreads();
  const int n  = t >> 2;
  const int kg = (t & 3) * 16;
  u16x8 o0, o1;
#pragma unroll
  for (int j = 0; j < 8; ++j) o0[j] = tile[kg + j][n];
#pragma unroll
  for (int j = 0; j < 8; ++j) o1[j] = tile[kg + 8 + j][n];
  unsigned short* dst = WbT + (size_t)(n0 + n) * K_DIM + k0 + kg;
  *(u16x8*)dst       = o0;
  *(u16x8*)(dst + 8) = o1;
}

// ---------- main GEMM: faithful lean 8-phase (m201 port) ----------
// Both operands bf16 via global_load_lds w16. Per phase: {<=12 ds_read +
// 2 DMA} -> [lgkm(8) if 12] -> BAR -> lgkm(0) -> setprio(16 MFMA) -> BAR.
// Staging: tile t ph1/2 stage A(t+1)->nxt; ph3/4 stage B(t+2) into the
// JUST-FREED halves of cur (b0 dead after ph1, b1 after ph2). One counted
// vmcnt(4) per tile at ph4 (retires A(t+1)+B(t+1); leaves B(t+2) in flight).
__global__ __launch_bounds__(512, 2) void gemm_lean(
    const unsigned short* __restrict__ Xb, const unsigned short* __restrict__ WbT,
    const float* __restrict__ bias, float* __restrict__ Z) {
  __shared__ __align__(16) unsigned short As[2][BM * BK];  // 64 KiB
  __shared__ __align__(16) unsigned short Bs[2][BN * BK];  // 64 KiB

  const int t   = (int)threadIdx.x;
  const int l   = t & 63;
  const int wid = t >> 6;
  const int wm  = wid >> 2;  // 0..1
  const int wn  = wid & 3;   // 0..3

  const int bid = (int)blockIdx.x;
  const int swz = (bid & 7) * 32 + (bid >> 3);  // bijective: 256 = 8*32
  const int m0  = (swz >> 2) * BM;
  const int n0  = (swz & 3) * BN;

  // fragment read offsets (XOR-swizzled; 0 conflicts measured R1..R12)
  const int abase = (wm * 128 + (l & 15)) * BK;
  const int bbase = (wn * 64 + (l & 15)) * BK;
  const int axk0  = (((l >> 4) + 0) ^ (l & 7)) << 3;
  const int axk1  = (((l >> 4) + 4) ^ (l & 7)) << 3;

  // staging: 4 chunks each; chunks {0,1}=half0 (rows 0..127), {2,3}=half1.
  // linear LDS dest, inverse-swizzled global source (rule #21).
  const unsigned short* a_src[4];
  const unsigned short* b_src[4];
  int sdst[4];
#pragma unroll
  for (int i = 0; i < 4; ++i) {
    const int c = i * 512 + t;
    const int r = c >> 3, g = c & 7;
    a_src[i] = Xb  + (size_t)(m0 + r) * K_DIM + (g ^ (r & 7)) * 8;
    b_src[i] = WbT + (size_t)(n0 + r) * K_DIM + (g ^ (r & 7)) * 8;
    sdst[i] = c * 8;
  }

  f32x4 acc[8][4] = {};        // 128 acc regs
  bf16x8 aF0[2][4], aF1[2][4]; // mig0 / mig1 A frags (32+32)
  bf16x8 bF0[2][2], bF1[2][2]; // nh0 / nh1 B frags (16+16)

#define SB0 __builtin_amdgcn_sched_barrier(0)
#define BAR __builtin_amdgcn_s_barrier()
#define WVM(N) do { asm volatile("s_waitcnt vmcnt(" #N ")" ::: "memory"); SB0; } while (0)
#define WLG(N) do { asm volatile("s_waitcnt lgkmcnt(" #N ")" ::: "memory"); SB0; } while (0)

#define DMA_AH(KT, BUF, H)                                                 \
  do {                                                                     \
    load_lds16(a_src[2 * (H)] + (KT), &As[BUF][sdst[2 * (H)]]);            \
    load_lds16(a_src[2 * (H) + 1] + (KT), &As[BUF][sdst[2 * (H) + 1]]);    \
  } while (0)
#define DMA_BH(KT, BUF, H)                                                 \
  do {                                                                     \
    load_lds16(b_src[2 * (H)] + (KT), &Bs[BUF][sdst[2 * (H)]]);            \
    load_lds16(b_src[2 * (H) + 1] + (KT), &Bs[BUF][sdst[2 * (H) + 1]]);    \
  } while (0)
#define RD_AF(DST, MIG, AB)                                                \
  do {                                                                     \
    _Pragma("unroll") for (int mi = 0; mi < 4; ++mi) {                     \
      DST[0][mi] = *(const bf16x8*)((AB) + abase + ((MIG)*4 + mi) * 1024 + axk0); \
      DST[1][mi] = *(const bf16x8*)((AB) + abase + ((MIG)*4 + mi) * 1024 + axk1); \
    }                                                                      \
  } while (0)
#define RD_BF(DST, NH, BB)                                                 \
  do {                                                                     \
    _Pragma("unroll") for (int nj = 0; nj < 2; ++nj) {                     \
      DST[0][nj] = *(const bf16x8*)((BB) + bbase + ((NH)*2 + nj) * 1024 + axk0); \
      DST[1][nj] = *(const bf16x8*)((BB) + bbase + ((NH)*2 + nj) * 1024 + axk1); \
    }                                                                      \
  } while (0)
#define QUAD(MIG, NH, AF, BF)                                              \
  do { __builtin_amdgcn_s_setprio(1);                                      \
    _Pragma("unroll") for (int kk = 0; kk < 2; ++kk)                       \
      _Pragma("unroll") for (int mi = 0; mi < 4; ++mi)                     \
        _Pragma("unroll") for (int nj = 0; nj < 2; ++nj)                   \
          acc[(MIG)*4 + mi][(NH)*2 + nj] =                                 \
              __builtin_amdgcn_mfma_f32_16x16x32_bf16(                     \
                  AF[kk][mi], BF[kk][nj], acc[(MIG)*4 + mi][(NH)*2 + nj],  \
                  0, 0, 0);                                                \
    __builtin_amdgcn_s_setprio(0);                                         \
  } while (0)

  // ---- prologue: stage A(0),B(0),A(1); retire tile-0's 8 loads ----
  DMA_AH(0, 0, 0); DMA_AH(0, 0, 1);
  DMA_BH(0, 0, 0); DMA_BH(0, 0, 1);
  DMA_AH(BK, 1, 0); DMA_AH(BK, 1, 1);
  WVM(4);                        // A(0)+B(0) done; A(1):4 in flight
  BAR;

  // ---- tile 0 (stages B(1)->nxt at ph1/2, B(2)->cur at ph3/4) ----
  {
    const unsigned short* Ab = As[0];
    const unsigned short* Bb = Bs[0];
    RD_AF(aF0, 0, Ab); RD_BF(bF0, 0, Bb);
    DMA_BH(BK, 1, 0);
    WLG(8); BAR; WLG(0);
    QUAD(0, 0, aF0, bF0);
    BAR;
    RD_BF(bF1, 1, Bb);
    DMA_BH(BK, 1, 1);
    BAR; WLG(0);
    QUAD(0, 1, aF0, bF1);
    BAR;
    RD_AF(aF1, 1, Ab);
    DMA_BH(2 * BK, 0, 0);
    BAR; WLG(0);
    QUAD(1, 1, aF1, bF1);
    BAR;
    DMA_BH(2 * BK, 0, 1);
    WVM(4);                      // retire A(1)+B(1); B(2):4 remain
    BAR;
    QUAD(1, 0, aF1, bF0);
    BAR;
  }

  // ---- steady: tt = 1 .. NT-3 ----
  for (int tt = 1; tt <= NT - 3; ++tt) {
    const int cur = tt & 1, nxt = cur ^ 1;
    const unsigned short* Ab = As[cur];
    const unsigned short* Bb = Bs[cur];
    const int kt1 = (tt + 1) * BK, kt2 = (tt + 2) * BK;
    // ph1: 12 reads; stage A(t+1)h0 -> nxt
    RD_AF(aF0, 0, Ab); RD_BF(bF0, 0, Bb);
    DMA_AH(kt1, nxt, 0);
    WLG(8); BAR; WLG(0);
    QUAD(0, 0, aF0, bF0);
    BAR;
    // ph2: 4 reads; stage A(t+1)h1 -> nxt
    RD_BF(bF1, 1, Bb);
    DMA_AH(kt1, nxt, 1);
    BAR; WLG(0);
    QUAD(0, 1, aF0, bF1);
    BAR;
    // ph3: 8 reads; stage B(t+2)h0 -> cur (b0 region dead since ph1)
    RD_AF(aF1, 1, Ab);
    DMA_BH(kt2, cur, 0);
    BAR; WLG(0);
    QUAD(1, 1, aF1, bF1);
    BAR;
    // ph4: stage B(t+2)h1 -> cur; ONE counted vmcnt per tile
    DMA_BH(kt2, cur, 1);
    WVM(4);                      // retire B(t+1)+A(t+1); B(t+2):4 remain
    BAR;
    QUAD(1, 0, aF1, bF0);
    BAR;
  }

  // ---- tile NT-2: stage A(NT-1) only; drain at ph4 ----
  {
    const int cur = (NT - 2) & 1, nxt = cur ^ 1;
    const unsigned short* Ab = As[cur];
    const unsigned short* Bb = Bs[cur];
    const int kt1 = (NT - 1) * BK;
    RD_AF(aF0, 0, Ab); RD_BF(bF0, 0, Bb);
    DMA_AH(kt1, nxt, 0);
    WLG(8); BAR; WLG(0);
    QUAD(0, 0, aF0, bF0);
    BAR;
    RD_BF(bF1, 1, Bb);
    DMA_AH(kt1, nxt, 1);
    BAR; WLG(0);
    QUAD(0, 1, aF0, bF1);
    BAR;
    RD_AF(aF1, 1, Ab);
    BAR; WLG(0);
    QUAD(1, 1, aF1, bF1);
    BAR;
    WVM(0);                      // tail drain: B(NT-1)+A(NT-1) all done
    BAR;
    QUAD(1, 0, aF1, bF0);
    BAR;
  }
  // ---- tile NT-1: pure compute, straight-line ----
  {
    const unsigned short* Ab = As[(NT - 1) & 1];
    const unsigned short* Bb = Bs[(NT - 1) & 1];
    RD_AF(aF0, 0, Ab); RD_BF(bF0, 0, Bb);
    WLG(0);
    QUAD(0, 0, aF0, bF0);
    RD_BF(bF1, 1, Bb);
    WLG(0);
    QUAD(0, 1, aF0, bF1);
    RD_AF(aF1, 1, Ab);
    WLG(0);
    QUAD(1, 1, aF1, bF1);
    QUAD(1, 0, aF1, bF0);
  }

  // ---- epilogue: + sign(bias); D frag: col = l&15, row = (l>>4)*4 + j ----
#pragma unroll
  for (int ni = 0; ni < 4; ++ni) {
    const int col = n0 + wn * 64 + ni * 16 + (l & 15);
    const float b  = bias[col];
    const float bs = (b > 0.f) ? 1.f : ((b < 0.f) ? -1.f : 0.f);
#pragma unroll
    for (int mi = 0; mi < 8; ++mi) {
      const int row = m0 + wm * 128 + mi * 16 + ((l >> 4) << 2);
#pragma unroll
      for (int j = 0; j < 4; ++j)
        Z[(size_t)(row + j) * N_DIM + col] = acc[mi][ni][j] + bs;
    }
  }
#undef SB0
#undef BAR
#undef WVM
#undef WLG
#undef DMA_AH
#undef DMA_BH
#undef RD_AF
#undef RD_BF
#undef QUAD
}

// ---------- fallback GEMM (R1-proven, fused fp32-A): needs 8 MiB ws ----------
__global__ __launch_bounds__(512, 2) void gemm_fused(
    const float* __restrict__ X, const unsigned short* __restrict__ WbT,
    const float* __restrict__ bias, float* __restrict__ Z) {
  __shared__ __align__(16) unsigned short As[2][BM * BK];
  __shared__ __align__(16) unsigned short Bs[2][BN * BK];
  const int t   = (int)threadIdx.x;
  const int l   = t & 63;
  const int wid = t >> 6;
  const int wm  = wid >> 2;
  const int wn  = wid & 3;
  const int bid = (int)blockIdx.x;
  const int swz = (bid & 7) * 32 + (bid >> 3);
  const int m0  = (swz >> 2) * BM;
  const int n0  = (swz & 3) * BN;
  const int abase = (wm * 128 + (l & 15)) * BK;
  const int bbase = (wn * 64 + (l & 15)) * BK;
  const int axk0  = (((l >> 4) + 0) ^ (l & 7)) << 3;
  const int axk1  = (((l >> 4) + 4) ^ (l & 7)) << 3;
  const float* a_src[4];
  int a_dst[4];
#pragma unroll
  for (int i = 0; i < 4; ++i) {
    const int d = i * 512 + t;
    const int row = d >> 3, g = d & 7;
    a_src[i] = X + (size_t)(m0 + row) * K_DIM + g * 8;
    a_dst[i] = row * BK + ((g ^ (row & 7)) << 3);
  }
  const unsigned short* b_src[4];
  int b_dst[4];
#pragma unroll
  for (int i = 0; i < 4; ++i) {
    const int c = i * 512 + t;
    const int n = c >> 3, gp = c & 7;
    b_src[i] = WbT + (size_t)(n0 + n) * K_DIM + (gp ^ (n & 7)) * 8;
    b_dst[i] = c * 8;
  }
  f32x4 acc[8][4] = {};
  f32x4 areg[4][2];
#define STAGE_A_LOAD(KT)                                                  \
  { _Pragma("unroll") for (int i = 0; i < 4; ++i) {                       \
      areg[i][0] = *(const f32x4*)(a_src[i] + (KT));                      \
      areg[i][1] = *(const f32x4*)(a_src[i] + (KT) + 4); } }
#define STAGE_A_WRITE(BUF)                                                \
  { _Pragma("unroll") for (int i = 0; i < 4; ++i) {                       \
      u16x8 v;                                                            \
      _Pragma("unroll") for (int j = 0; j < 4; ++j) {                     \
        v[j] = (unsigned short)f2bf(areg[i][0][j]);                       \
        v[4 + j] = (unsigned short)f2bf(areg[i][1][j]); }                 \
      *(u16x8*)(&As[BUF][a_dst[i]]) = v; } }
#define STAGE_B(KT, BUF)                                                  \
  { _Pragma("unroll") for (int i = 0; i < 4; ++i)                         \
      load_lds16(b_src[i] + (KT), &Bs[BUF][b_dst[i]]); }
#define COMPUTE(CUR)                                                      \
  { const unsigned short* Ab = As[CUR];                                   \
    const unsigned short* Bb = Bs[CUR];                                   \
    _Pragma("unroll") for (int kk = 0; kk < 2; ++kk) {                    \
      const int axk = kk ? axk1 : axk0;                                   \
      bf16x8 bf[4];                                                       \
      _Pragma("unroll") for (int ni = 0; ni < 4; ++ni)                    \
        bf[ni] = *(const bf16x8*)(Bb + bbase + ni * 1024 + axk);          \
      _Pragma("unroll") for (int mi = 0; mi < 8; ++mi) {                  \
        const bf16x8 af = *(const bf16x8*)(Ab + abase + mi * 1024 + axk); \
        _Pragma("unroll") for (int ni = 0; ni < 4; ++ni)                  \
          acc[mi][ni] = __builtin_amdgcn_mfma_f32_16x16x32_bf16(          \
              af, bf[ni], acc[mi][ni], 0, 0, 0); } } }
  STAGE_A_LOAD(0);
  STAGE_B(0, 0);
  STAGE_A_WRITE(0);
  __syncthreads();
  int cur = 0;
  for (int tt = 0; tt < NT - 1; ++tt) {
    const int ktn = (tt + 1) * BK;
    STAGE_A_LOAD(ktn);
    STAGE_B(ktn, cur ^ 1);
    COMPUTE(cur);
    STAGE_A_WRITE(cur ^ 1);
    __syncthreads();
    cur ^= 1;
  }
  COMPUTE(cur);
#pragma unroll
  for (int ni = 0; ni < 4; ++ni) {
    const int col = n0 + wn * 64 + ni * 16 + (l & 15);
    const float b  = bias[col];
    const float bs = (b > 0.f) ? 1.f : ((b < 0.f) ? -1.f : 0.f);
#pragma unroll
    for (int mi = 0; mi < 8; ++mi) {
      const int row = m0 + wm * 128 + mi * 16 + ((l >> 4) << 2);
#pragma unroll
      for (int j = 0; j < 4; ++j)
        Z[(size_t)(row + j) * N_DIM + col] = acc[mi][ni][j] + bs;
    }
  }
#undef STAGE_A_LOAD
#undef STAGE_A_WRITE
#undef STAGE_B
#undef COMPUTE
}

// ---------- slow-but-correct fallback ----------
__global__ __launch_bounds__(256) void naive_fb(
    const float* __restrict__ X, const float* __restrict__ W,
    const float* __restrict__ bias, float* __restrict__ Z) {
  const size_t id = (size_t)blockIdx.x * 256 + threadIdx.x;
  const int m = (int)(id >> 10), n = (int)(id & 1023);
  float acc = 0.f;
  for (int k = 0; k < K_DIM; ++k) {
    const float w = W[(size_t)k * N_DIM + n];
    const float s = (w > 0.f) ? 1.f : ((w < 0.f) ? -1.f : 0.f);
    acc += X[(size_t)m * K_DIM + k] * s;
  }
  const float b = bias[n];
  Z[id] = acc + ((b > 0.f) ? 1.f : ((b < 0.f) ? -1.f : 0.f));
}

extern "C" void kernel_launch(void* const* d_in, const int* in_sizes, int n_in,
                              void* d_out, int out_size, void* d_ws, size_t ws_size,
                              hipStream_t stream) {
  const float* X    = (const float*)d_in[0];
  const float* W    = (const float*)d_in[1];
  const float* bias = (const float*)d_in[2];
  float* Z = (float*)d_out;

  const size_t needW = (size_t)N_DIM * K_DIM * sizeof(unsigned short);  // 8 MiB
  const size_t needX = (size_t)M_DIM * K_DIM * sizeof(unsigned short);  // 128 MiB
  if (ws_size >= needW + needX) {
    unsigned short* WbT = (unsigned short*)d_ws;
    unsigned short* Xb  = (unsigned short*)((char*)d_ws + needW);
    xcvt<<<dim3(2048), dim3(256), 0, stream>>>(X, Xb);
    wsign_transpose<<<dim3((K_DIM / 64) * (N_DIM / 64)), dim3(256), 0, stream>>>(W, WbT);
    gemm_lean<<<dim3((M_DIM / BM) * (N_DIM / BN)), dim3(512), 0, stream>>>(Xb, WbT, bias, Z);
  } else if (ws_size >= needW) {
    unsigned short* WbT = (unsigned short*)d_ws;
    wsign_transpose<<<dim3((K_DIM / 64) * (N_DIM / 64)), dim3(256), 0, stream>>>(W, WbT);
    gemm_fused<<<dim3((M_DIM / BM) * (N_DIM / BN)), dim3(512), 0, stream>>>(X, WbT, bias, Z);
  } else {
    naive_fb<<<dim3((size_t)M_DIM * N_DIM / 256), dim3(256), 0, stream>>>(X, W, bias, Z);
  }
}